// Round 1
// baseline (190.497 us; speedup 1.0000x reference)
//
#include <hip/hip_runtime.h>

#define TT 3
#define CCH 32
#define HH 256
#define WW 256
#define PS 7
#define WS 8
#define KK 7
#define NQ 64          // nH == nW
#define QPB 16         // qw queries per block
#define V1W 80         // v1 row stride (floats), 16B-aligned rows
#define V1P (14*V1W + 8)   // v1 plane stride = 1128 (pad 8 to break bank aliasing)
#define V0W 72         // v0 row stride
#define V0P (7*V0W)    // 504

__device__ __forceinline__ int refl(int i, int n) {
    i = i < 0 ? -i : i;
    return i >= n ? 2*(n-1) - i : i;
}

__global__ __launch_bounds__(256, 3)
void nls_kernel(const float* __restrict__ vid0, const float* __restrict__ vid1,
                float* __restrict__ out) {
    __shared__ float v1s[8 * V1P];   // 36096 B
    __shared__ float v0s[8 * V0P];   // 16128 B

    const int bx   = blockIdx.x;
    const int t    = bx >> 8;            // / 256
    const int rem  = bx & 255;
    const int qy   = rem >> 2;           // qh index 0..63
    const int q0   = (rem & 3) * QPB;    // qw base index
    const int qh   = qy * 4;

    const int tid   = threadIdx.x;
    const int qwi   = tid >> 4;          // 0..15
    const int cg    = tid & 15;
    const int clane = cg & 7;            // channel lane 0..7
    const int shh   = cg >> 3;           // sh half: 0 -> sh in [-4,-1], 1 -> [0,3]

    float acc[4][8];
#pragma unroll
    for (int a = 0; a < 4; ++a)
#pragma unroll
        for (int b = 0; b < 8; ++b) acc[a][b] = 0.f;

#pragma unroll 1
    for (int s = 0; s < 4; ++s) {
        const int c0 = 8 * s;
        __syncthreads();
        // ---- fill v1 LDS: 8 ch x 14 rows x 80 cols, pre-reflected halo ----
        for (int idx = tid; idx < 8 * 14 * V1W; idx += 256) {
            int ch = idx / (14 * V1W);
            int r2 = idx - ch * (14 * V1W);
            int r  = r2 / V1W;
            int wi = r2 - r * V1W;
            int h  = refl(qh + r - 7, HH);
            int w  = refl(4 * q0 + wi - 7, WW);
            v1s[ch * V1P + r * V1W + wi] =
                vid1[(((t * CCH + c0 + ch) * HH) + h) * WW + w];
        }
        // ---- fill v0 LDS: 8 ch x 7 rows x 72 cols ----
        for (int idx = tid; idx < 8 * 7 * V0W; idx += 256) {
            int ch = idx / (7 * V0W);
            int r2 = idx - ch * (7 * V0W);
            int i  = r2 / V0W;
            int wi = r2 - i * V0W;
            int h  = refl(qh + i - 3, HH);
            int w  = refl(4 * q0 + wi - 7, WW);
            v0s[ch * V0P + i * V0W + wi] =
                vid0[(((t * CCH + c0 + ch) * HH) + h) * WW + w];
        }
        __syncthreads();

        // ---- compute: this thread's channel = c0 + clane ----
        float x[7][8];
        const float* v0b = &v0s[clane * V0P + 4 * qwi + 4];
#pragma unroll
        for (int i = 0; i < 7; ++i) {
            const float4* px = (const float4*)(v0b + i * V0W);
            float4 xa = px[0], xb = px[1];
            x[i][0]=xa.x; x[i][1]=xa.y; x[i][2]=xa.z; x[i][3]=xa.w;
            x[i][4]=xb.x; x[i][5]=xb.y; x[i][6]=xb.z; x[i][7]=xb.w;
        }
        const float* v1b = &v1s[clane * V1P + 4 * qwi];
#pragma unroll
        for (int rr = 0; rr < 10; ++rr) {
            const float4* py = (const float4*)(v1b + (rr + 4 * shh) * V1W);
            float4 ya = py[0], yb = py[1], yc = py[2], yd = py[3];
            float y[16];
            y[0]=ya.x;  y[1]=ya.y;  y[2]=ya.z;  y[3]=ya.w;
            y[4]=yb.x;  y[5]=yb.y;  y[6]=yb.z;  y[7]=yb.w;
            y[8]=yc.x;  y[9]=yc.y;  y[10]=yc.z; y[11]=yc.w;
            y[12]=yd.x; y[13]=yd.y; y[14]=yd.z; y[15]=yd.w;
#pragma unroll
            for (int shl = 0; shl < 4; ++shl) {
                const int i = rr - shl;          // compile-time after unroll
                if (i >= 0 && i < 7) {
#pragma unroll
                    for (int sw = 0; sw < 8; ++sw)
#pragma unroll
                        for (int j = 0; j < 7; ++j)
                            acc[shl][sw] += x[i][j] * y[sw + j];
                }
            }
        }
    }

    // ---- reduce across the 8 channel lanes (bits 0..2 of lane id) ----
#pragma unroll
    for (int m = 1; m <= 4; m <<= 1)
#pragma unroll
        for (int a = 0; a < 4; ++a)
#pragma unroll
            for (int b = 0; b < 8; ++b)
                acc[a][b] += __shfl_xor(acc[a][b], m, 64);

    __syncthreads();               // done reading v1s; overlay as dists buffer
    float* dlds = v1s;             // 16 queries x 64 shifts = 4 KB
    if (clane == 0) {
#pragma unroll
        for (int a = 0; a < 4; ++a)
#pragma unroll
            for (int b = 0; b < 8; ++b)
                dlds[qwi * 64 + (shh * 4 + a) * 8 + b] = acc[a][b];
    }
    __syncthreads();

    // ---- top-7 per query (16 threads) ----
    if (tid < QPB) {
        const float* d = &dlds[tid * 64];
        const int qx = q0 + tid;
        const int q  = (t * NQ + qy) * NQ + qx;
        unsigned long long chosen = 0ull;
        for (int k = 0; k < KK; ++k) {
            float best = -3.4e38f;
            int bi = 0;
            for (int j = 0; j < 64; ++j) {
                if ((chosen >> j) & 1ull) continue;
                float v = d[j];
                if (j == 36) v += 1e30f;       // self bias, selection only
                if (v > best) { best = v; bi = j; }
            }
            chosen |= 1ull << bi;
            const int dh = (bi >> 3) - 4;
            const int dw = (bi & 7) - 4;
            const int hh = refl(qh + dh, HH);
            const int ww = refl(qx * 4 + dw, WW);
            out[q * KK + k] = d[bi];
            float* oi = out + (TT * NQ * NQ * KK) + (q * KK + k) * 3;
            oi[0] = (float)t;
            oi[1] = (float)hh;
            oi[2] = (float)ww;
        }
    }
}

extern "C" void kernel_launch(void* const* d_in, const int* in_sizes, int n_in,
                              void* d_out, int out_size, void* d_ws, size_t ws_size,
                              hipStream_t stream) {
    (void)in_sizes; (void)n_in; (void)d_ws; (void)ws_size; (void)out_size;
    const float* vid0 = (const float*)d_in[0];
    const float* vid1 = (const float*)d_in[1];
    float* out = (float*)d_out;
    nls_kernel<<<dim3(TT * NQ * (NQ / QPB)), dim3(256), 0, stream>>>(vid0, vid1, out);
}

// Round 2
// 126.572 us; speedup vs baseline: 1.5050x; 1.5050x over previous
//
#include <hip/hip_runtime.h>

#define TT 3
#define CCH 32
#define HH 256
#define WW 256
#define KK 7
#define NQ 64
#define QPB 16
#define V1W 80
#define V1N (14*V1W)      // 1120 floats per channel plane
#define V1P (V1N + 8)     // 1128 (mod 32 == 8 -> clane offsets 0,8,16,24)
#define V0W 72
#define V0N (7*V0W)       // 504
#define V0P (V0N + 16)    // 520 (mod 32 == 8)
#define CHC 4             // channels per chunk

__device__ __forceinline__ int refl(int i, int n) {
    i = i < 0 ? -i : i;
    return i >= n ? 2*(n-1) - i : i;
}

__global__ __launch_bounds__(256, 4)
void nls_kernel(const float* __restrict__ vid0, const float* __restrict__ vid1,
                float* __restrict__ out) {
    __shared__ float v1s[CHC * V1P];   // 18048 B
    __shared__ float v0s[CHC * V0P];   // 8320 B   -> 26368 B total

    const int bx  = blockIdx.x;
    const int t   = bx >> 8;
    const int rem = bx & 255;
    const int qy  = rem >> 2;
    const int q0  = (rem & 3) * QPB;
    const int qh  = qy * 4;
    const int w0  = 4*q0 - 7;

    const int tid   = threadIdx.x;
    const int qwi   = tid & 15;          // query within strip
    const int clane = (tid >> 4) & 3;    // channel lane (intra-wave bits 4,5)
    const int shq   = tid >> 6;          // wave id -> sh pair {2shq-4, 2shq-3}

    // ---- precompute per-thread staging offsets (channel-independent) ----
    int off1[5];
#pragma unroll
    for (int k = 0; k < 5; ++k) {
        int idx = tid + 256*k;
        if (idx < V1N) {
            int r = idx / V1W, wi = idx - r*V1W;
            off1[k] = refl(qh + r - 7, HH) * WW + refl(w0 + wi, WW);
        } else off1[k] = 0;
    }
    int off0[2];
#pragma unroll
    for (int k = 0; k < 2; ++k) {
        int idx = tid + 256*k;
        if (idx < V0N) {
            int r = idx / V0W, wi = idx - r*V0W;
            off0[k] = refl(qh + r - 3, HH) * WW + refl(w0 + wi, WW);
        } else off0[k] = 0;
    }

    float acc[2][8];
#pragma unroll
    for (int l = 0; l < 2; ++l)
#pragma unroll
        for (int b = 0; b < 8; ++b) acc[l][b] = 0.f;

    const float* g0 = vid0 + (size_t)t * (CCH*HH*WW);
    const float* g1 = vid1 + (size_t)t * (CCH*HH*WW);

#pragma unroll 1
    for (int s = 0; s < 8; ++s) {
        const int cb = CHC * s * (HH*WW);
        __syncthreads();
        // ---- stage: load to regs, then LDS (offsets precomputed) ----
        float t1[CHC][5];
        float t0v[CHC][2];
#pragma unroll
        for (int ch = 0; ch < CHC; ++ch) {
            const float* p1 = g1 + cb + ch*(HH*WW);
            const float* p0 = g0 + cb + ch*(HH*WW);
#pragma unroll
            for (int k = 0; k < 4; ++k) t1[ch][k] = p1[off1[k]];
            t1[ch][4]  = (tid < V1N - 1024) ? p1[off1[4]] : 0.f;
            t0v[ch][0] = p0[off0[0]];
            t0v[ch][1] = (tid < V0N - 256) ? p0[off0[1]] : 0.f;
        }
#pragma unroll
        for (int ch = 0; ch < CHC; ++ch) {
#pragma unroll
            for (int k = 0; k < 4; ++k) v1s[ch*V1P + tid + 256*k] = t1[ch][k];
            if (tid < V1N - 1024) v1s[ch*V1P + tid + 1024] = t1[ch][4];
            v0s[ch*V0P + tid] = t0v[ch][0];
            if (tid < V0N - 256) v0s[ch*V0P + tid + 256] = t0v[ch][1];
        }
        __syncthreads();

        // ---- compute: my channel = 4s + clane ----
        float x[7][8];
        const float* xb = &v0s[clane*V0P + 4*qwi + 4];
#pragma unroll
        for (int i = 0; i < 7; ++i) {
            float4 a = *(const float4*)(xb + i*V0W);
            float4 b = *(const float4*)(xb + i*V0W + 4);
            x[i][0]=a.x; x[i][1]=a.y; x[i][2]=a.z; x[i][3]=a.w;
            x[i][4]=b.x; x[i][5]=b.y; x[i][6]=b.z; x[i][7]=b.w;
        }
        const float* yb = &v1s[clane*V1P + (2*shq)*V1W + 4*qwi];
#pragma unroll
        for (int rr = 0; rr < 8; ++rr) {
            const float4* py = (const float4*)(yb + rr*V1W);
            float4 A = py[0], B = py[1], C = py[2], D = py[3];
            float y[16];
            y[0]=A.x;  y[1]=A.y;  y[2]=A.z;  y[3]=A.w;
            y[4]=B.x;  y[5]=B.y;  y[6]=B.z;  y[7]=B.w;
            y[8]=C.x;  y[9]=C.y;  y[10]=C.z; y[11]=C.w;
            y[12]=D.x; y[13]=D.y; y[14]=D.z; y[15]=D.w;
            if (rr < 7) {      // l=0, patch row i = rr
#pragma unroll
                for (int sw = 0; sw < 8; ++sw)
#pragma unroll
                    for (int j = 0; j < 7; ++j)
                        acc[0][sw] += x[rr][j] * y[sw + j];
            }
            if (rr >= 1) {     // l=1, patch row i = rr-1
#pragma unroll
                for (int sw = 0; sw < 8; ++sw)
#pragma unroll
                    for (int j = 0; j < 7; ++j)
                        acc[1][sw] += x[rr-1][j] * y[sw + j];
            }
        }
    }

    // ---- reduce across 4 channel lanes (intra-wave bits 4,5) ----
#pragma unroll
    for (int m = 16; m <= 32; m <<= 1)
#pragma unroll
        for (int l = 0; l < 2; ++l)
#pragma unroll
            for (int b = 0; b < 8; ++b)
                acc[l][b] += __shfl_xor(acc[l][b], m, 64);

    __syncthreads();                 // all v1s reads done; overlay dists
    float* dlds = v1s;               // 16 queries x 64 shifts
    if (clane == 0) {
#pragma unroll
        for (int l = 0; l < 2; ++l)
#pragma unroll
            for (int b = 0; b < 8; ++b)
                dlds[qwi*64 + (2*shq + l)*8 + b] = acc[l][b];
    }
    __syncthreads();

    // ---- top-7: 16 threads per query, shuffle-reduce argmax ----
    {
        const int q16 = tid >> 4;
        const int l16 = tid & 15;
        const float* d = &dlds[q16 * 64];
        const int j0 = l16 * 4;
        float cv[4];
#pragma unroll
        for (int jj = 0; jj < 4; ++jj) {
            float v = d[j0 + jj];
            if (j0 + jj == 36) v += 1e30f;    // self bias (selection only)
            cv[jj] = v;
        }
        unsigned mask = 0;
        const int qx = q0 + q16;
        const int q  = (t*NQ + qy)*NQ + qx;
        float* od = out + q*KK;
        float* oi = out + (size_t)TT*NQ*NQ*KK + (size_t)q*KK*3;
        for (int k = 0; k < KK; ++k) {
            float best = -3.4e38f; int bi = 1 << 30;
#pragma unroll
            for (int jj = 0; jj < 4; ++jj)
                if (!(mask & (1u << jj)) && cv[jj] > best) { best = cv[jj]; bi = j0 + jj; }
#pragma unroll
            for (int m = 1; m <= 8; m <<= 1) {
                float ob = __shfl_xor(best, m, 64);
                int  obi = __shfl_xor(bi,  m, 64);
                if (ob > best || (ob == best && obi < bi)) { best = ob; bi = obi; }
            }
            if ((bi >> 2) == l16) mask |= 1u << (bi & 3);
            if (l16 == 0) {
                od[k] = d[bi];                 // unbiased value
                int dh = (bi >> 3) - 4;
                int dw = (bi & 7) - 4;
                oi[k*3 + 0] = (float)t;
                oi[k*3 + 1] = (float)refl(qh + dh, HH);
                oi[k*3 + 2] = (float)refl(qx*4 + dw, WW);
            }
        }
    }
}

extern "C" void kernel_launch(void* const* d_in, const int* in_sizes, int n_in,
                              void* d_out, int out_size, void* d_ws, size_t ws_size,
                              hipStream_t stream) {
    (void)in_sizes; (void)n_in; (void)d_ws; (void)ws_size; (void)out_size;
    const float* vid0 = (const float*)d_in[0];
    const float* vid1 = (const float*)d_in[1];
    float* out = (float*)d_out;
    nls_kernel<<<dim3(TT * NQ * (NQ / QPB)), dim3(256), 0, stream>>>(vid0, vid1, out);
}